// Round 1
// baseline (349.120 us; speedup 1.0000x reference)
//
#include <hip/hip_runtime.h>
#include <hip/hip_bf16.h>

#define NN 512      // nodes per graph
#define NE 8192     // edges per graph
#define NG 128      // graphs (B*G)
#define FH 128      // feature/hidden dim
#define BN_EPS 1e-5f

// ---------------- K1: degrees + rsqrt norms + CSR (by dst) build ----------------
__global__ __launch_bounds__(256) void k_build(const int* __restrict__ edges,
                                               float* __restrict__ rs_out,
                                               float* __restrict__ rs_in,
                                               int* __restrict__ row_ofs,
                                               int* __restrict__ csr_src) {
    int g = blockIdx.x;
    int tid = threadIdx.x;
    const int* src = edges + (size_t)g * 2 * NE;
    const int* dst = src + NE;

    __shared__ int degO[NN], degI[NN];
    __shared__ int scanA[NN], scanB[NN];
    __shared__ int fill[NN];

    for (int i = tid; i < NN; i += 256) { degO[i] = 0; degI[i] = 0; }
    __syncthreads();
    for (int e = tid; e < NE; e += 256) {
        atomicAdd(&degO[src[e]], 1);
        atomicAdd(&degI[dst[e]], 1);
    }
    __syncthreads();
    for (int i = tid; i < NN; i += 256) {
        int dO = degO[i], dI = degI[i];
        rs_out[g * NN + i] = rsqrtf((float)max(dO, 1));
        rs_in [g * NN + i] = rsqrtf((float)max(dI, 1));
        scanA[i] = dI;
    }
    __syncthreads();
    // Hillis-Steele inclusive scan over 512 in-degrees (double-buffered)
    int* sA = scanA; int* sB = scanB;
    for (int off = 1; off < NN; off <<= 1) {
        for (int i = tid; i < NN; i += 256) {
            int v = sA[i];
            if (i >= off) v += sA[i - off];
            sB[i] = v;
        }
        __syncthreads();
        int* t = sA; sA = sB; sB = t;
    }
    for (int i = tid; i < NN; i += 256) {
        int excl = (i == 0) ? 0 : sA[i - 1];
        fill[i] = excl;
        row_ofs[g * 513 + i] = excl;
    }
    if (tid == 0) row_ofs[g * 513 + NN] = sA[NN - 1];
    __syncthreads();
    for (int e = tid; e < NE; e += 256) {
        int d = dst[e];
        int pos = atomicAdd(&fill[d], 1);
        csr_src[(size_t)g * NE + pos] = src[e];
    }
}

// ---------------- K2/K4: Y = (X @ W) * rs_row  (fp32, 64-row tiles) ----------------
__device__ inline void fma4(float4& a, float s, const float4& w) {
    a.x += s * w.x; a.y += s * w.y; a.z += s * w.z; a.w += s * w.w;
}

__global__ __launch_bounds__(256) void k_gemm(const float* __restrict__ X,
                                              const float* __restrict__ W,
                                              const float* __restrict__ rs,
                                              float* __restrict__ Y) {
    __shared__ float xs[64][FH];   // 32 KB
    int tid = threadIdx.x;
    size_t r0 = (size_t)blockIdx.x * 64;

    // stage X tile (64x128 floats = 2048 float4), coalesced
    const float4* Xv = (const float4*)(X + r0 * FH);
    float4* xsv = (float4*)&xs[0][0];
#pragma unroll
    for (int i = 0; i < 8; i++) xsv[tid + i * 256] = Xv[tid + i * 256];
    __syncthreads();

    int tx = tid & 31;        // col group: 4 consecutive cols
    int ty = tid >> 5;        // row group: 8 consecutive rows
    int c4 = tx * 4;
    int row0 = ty * 8;

    float4 acc[8];
#pragma unroll
    for (int i = 0; i < 8; i++) acc[i] = make_float4(0.f, 0.f, 0.f, 0.f);

    for (int k = 0; k < FH; k += 4) {
        float4 w0 = *(const float4*)(W + (size_t)(k + 0) * FH + c4);
        float4 w1 = *(const float4*)(W + (size_t)(k + 1) * FH + c4);
        float4 w2 = *(const float4*)(W + (size_t)(k + 2) * FH + c4);
        float4 w3 = *(const float4*)(W + (size_t)(k + 3) * FH + c4);
#pragma unroll
        for (int i = 0; i < 8; i++) {
            float4 xv = *(const float4*)&xs[row0 + i][k];
            fma4(acc[i], xv.x, w0);
            fma4(acc[i], xv.y, w1);
            fma4(acc[i], xv.z, w2);
            fma4(acc[i], xv.w, w3);
        }
    }

#pragma unroll
    for (int i = 0; i < 8; i++) {
        size_t r = r0 + row0 + i;
        float s = rs[r];
        float4 v = acc[i];
        v.x *= s; v.y *= s; v.z *= s; v.w *= s;
        *(float4*)(Y + r * FH + c4) = v;
    }
}

// ---------------- K3: h[d] = relu(rs_in[d] * sum_{e in row(d)} Y[src_e] + b) ----------------
__global__ __launch_bounds__(256) void k_gather(const float* __restrict__ Y,
                                                const int* __restrict__ row_ofs,
                                                const int* __restrict__ csr_src,
                                                const float* __restrict__ rs_in,
                                                const float* __restrict__ bias,
                                                float* __restrict__ H) {
    int g  = blockIdx.x;
    int fc = blockIdx.y;   // 0..3  feature chunk of 32
    int nq = blockIdx.z;   // 0..3  node quarter of 128
    int tid = threadIdx.x;
    int f  = fc * 32 + (tid & 31);
    int dg = tid >> 5;     // 0..7
    const float* Yg = Y + (size_t)g * NN * FH;
    const int* ro = row_ofs + g * 513;
    const int* cs = csr_src + (size_t)g * NE;
    float bv = bias[f];

    for (int di = 0; di < 16; di++) {
        int d = nq * 128 + dg * 16 + di;
        int e0 = ro[d], e1 = ro[d + 1];
        float a0 = 0.f, a1 = 0.f, a2 = 0.f, a3 = 0.f;
        int e = e0;
        for (; e + 3 < e1; e += 4) {
            int s0 = cs[e], s1 = cs[e + 1], s2 = cs[e + 2], s3 = cs[e + 3];
            a0 += Yg[(size_t)s0 * FH + f];
            a1 += Yg[(size_t)s1 * FH + f];
            a2 += Yg[(size_t)s2 * FH + f];
            a3 += Yg[(size_t)s3 * FH + f];
        }
        for (; e < e1; e++) a0 += Yg[(size_t)cs[e] * FH + f];
        float acc = (a0 + a1) + (a2 + a3);
        float h = rs_in[g * NN + d] * acc + bv;
        H[((size_t)g * NN + d) * FH + f] = fmaxf(h, 0.f);
    }
}

// ---------------- K5: gather2 + fused mean over nodes -> emb accumulation ----------------
__global__ __launch_bounds__(256) void k_gather_mean(const float* __restrict__ Y,
                                                     const int* __restrict__ row_ofs,
                                                     const int* __restrict__ csr_src,
                                                     const float* __restrict__ rs_in,
                                                     const float* __restrict__ bias,
                                                     float* __restrict__ emb) {
    int g  = blockIdx.x;
    int fc = blockIdx.y;
    int nq = blockIdx.z;
    int tid = threadIdx.x;
    int lf = tid & 31;
    int f  = fc * 32 + lf;
    int dg = tid >> 5;
    const float* Yg = Y + (size_t)g * NN * FH;
    const int* ro = row_ofs + g * 513;
    const int* cs = csr_src + (size_t)g * NE;
    float bv = bias[f];

    float sum = 0.f;
    for (int di = 0; di < 16; di++) {
        int d = nq * 128 + dg * 16 + di;
        int e0 = ro[d], e1 = ro[d + 1];
        float a0 = 0.f, a1 = 0.f, a2 = 0.f, a3 = 0.f;
        int e = e0;
        for (; e + 3 < e1; e += 4) {
            int s0 = cs[e], s1 = cs[e + 1], s2 = cs[e + 2], s3 = cs[e + 3];
            a0 += Yg[(size_t)s0 * FH + f];
            a1 += Yg[(size_t)s1 * FH + f];
            a2 += Yg[(size_t)s2 * FH + f];
            a3 += Yg[(size_t)s3 * FH + f];
        }
        for (; e < e1; e++) a0 += Yg[(size_t)cs[e] * FH + f];
        float acc = (a0 + a1) + (a2 + a3);
        float h = rs_in[g * NN + d] * acc + bv;
        sum += fmaxf(h, 0.f);
    }
    __shared__ float red[8][32];
    red[dg][lf] = sum;
    __syncthreads();
    if (dg == 0) {
        float s = 0.f;
#pragma unroll
        for (int j = 0; j < 8; j++) s += red[j][lf];
        atomicAdd(&emb[g * FH + f], s);
    }
}

// ---------------- K6: z = emb/512 @ Wt + bt; BN eval; relu ----------------
__global__ __launch_bounds__(128) void k_head(const float* __restrict__ emb,
                                              const float* __restrict__ Wt,
                                              const float* __restrict__ bt,
                                              const float* __restrict__ gamma,
                                              const float* __restrict__ beta,
                                              const float* __restrict__ rmean,
                                              const float* __restrict__ rvar,
                                              float* __restrict__ out) {
    int g = blockIdx.x;
    int j = threadIdx.x;
    __shared__ float e[FH];
    e[j] = emb[g * FH + j] * (1.0f / (float)NN);
    __syncthreads();
    float acc = bt[j];
    for (int k = 0; k < FH; k++) acc += e[k] * Wt[(size_t)k * FH + j];
    float z = gamma[j] * (acc - rmean[j]) * rsqrtf(rvar[j] + BN_EPS) + beta[j];
    out[g * FH + j] = fmaxf(z, 0.f);
}

extern "C" void kernel_launch(void* const* d_in, const int* in_sizes, int n_in,
                              void* d_out, int out_size, void* d_ws, size_t ws_size,
                              hipStream_t stream) {
    const float* feats = (const float*)d_in[0];
    const int*   edges = (const int*)d_in[1];
    const float* W0    = (const float*)d_in[2];
    const float* b0    = (const float*)d_in[3];
    const float* W1    = (const float*)d_in[4];
    const float* b1    = (const float*)d_in[5];
    const float* Wt    = (const float*)d_in[6];
    const float* bt    = (const float*)d_in[7];
    const float* gamma = (const float*)d_in[8];
    const float* beta  = (const float*)d_in[9];
    const float* rmean = (const float*)d_in[10];
    const float* rvar  = (const float*)d_in[11];
    float* out = (float*)d_out;

    // workspace layout (all sizes in elements)
    char* w = (char*)d_ws;
    float* rs_out  = (float*)w;                     w += sizeof(float) * NG * NN;        // 256 KB
    float* rs_in   = (float*)w;                     w += sizeof(float) * NG * NN;        // 256 KB
    int*   row_ofs = (int*)w;                       w += sizeof(int) * NG * 520;         // ~266 KB
    int*   csr_src = (int*)w;                       w += sizeof(int) * (size_t)NG * NE;  // 4 MB
    float* Y       = (float*)w;                     w += sizeof(float) * (size_t)NG * NN * FH; // 32 MB
    float* H1      = (float*)w;                     w += sizeof(float) * (size_t)NG * NN * FH; // 32 MB
    float* emb     = (float*)w;                     w += sizeof(float) * NG * FH;        // 64 KB

    // K1: build norms + CSR
    k_build<<<NG, 256, 0, stream>>>(edges, rs_out, rs_in, row_ofs, csr_src);

    // zero emb accumulator (ws is poisoned 0xAA before every launch)
    hipMemsetAsync(emb, 0, sizeof(float) * NG * FH, stream);

    // K2: Y = (feats @ W0) * rs_out
    k_gemm<<<(NG * NN) / 64, 256, 0, stream>>>(feats, W0, rs_out, Y);

    // K3: h1 = relu(rs_in * gather(Y) + b0)
    k_gather<<<dim3(NG, 4, 4), 256, 0, stream>>>(Y, row_ofs, csr_src, rs_in, b0, H1);

    // K4: Y = (h1 @ W1) * rs_out
    k_gemm<<<(NG * NN) / 64, 256, 0, stream>>>(H1, W1, rs_out, Y);

    // K5: emb[g] += sum_d relu(rs_in * gather(Y) + b1)   (mean applied in K6)
    k_gather_mean<<<dim3(NG, 4, 4), 256, 0, stream>>>(Y, row_ofs, csr_src, rs_in, b1, emb);

    // K6: per-graph GEMV + BN + relu
    k_head<<<NG, 128, 0, stream>>>(emb, Wt, bt, gamma, beta, rmean, rvar, out);

    (void)in_sizes; (void)n_in; (void)out_size; (void)ws_size;
}

// Round 2
// 276.670 us; speedup vs baseline: 1.2619x; 1.2619x over previous
//
#include <hip/hip_runtime.h>
#include <hip/hip_bf16.h>

#define NN 512      // nodes per graph
#define NE 8192     // edges per graph
#define NG 128      // graphs (B*G)
#define FH 128      // feature/hidden dim
#define BN_EPS 1e-5f

__device__ inline void f4acc(float4& a, const float4& b) {
    a.x += b.x; a.y += b.y; a.z += b.z; a.w += b.w;
}

// ---------------- K1: degrees + rsqrt norms + CSR (by dst) build ----------------
__global__ __launch_bounds__(256) void k_build(const int* __restrict__ edges,
                                               float* __restrict__ rs_out,
                                               float* __restrict__ rs_in,
                                               int* __restrict__ row_ofs,
                                               int* __restrict__ csr_src) {
    int g = blockIdx.x;
    int tid = threadIdx.x;
    const int* src = edges + (size_t)g * 2 * NE;
    const int* dst = src + NE;

    __shared__ int degO[NN], degI[NN];
    __shared__ int scanA[NN], scanB[NN];
    __shared__ int fill[NN];

    for (int i = tid; i < NN; i += 256) { degO[i] = 0; degI[i] = 0; }
    __syncthreads();
    for (int e = tid; e < NE; e += 256) {
        atomicAdd(&degO[src[e]], 1);
        atomicAdd(&degI[dst[e]], 1);
    }
    __syncthreads();
    for (int i = tid; i < NN; i += 256) {
        int dO = degO[i], dI = degI[i];
        rs_out[g * NN + i] = rsqrtf((float)max(dO, 1));
        rs_in [g * NN + i] = rsqrtf((float)max(dI, 1));
        scanA[i] = dI;
    }
    __syncthreads();
    // Hillis-Steele inclusive scan over 512 in-degrees (double-buffered)
    int* sA = scanA; int* sB = scanB;
    for (int off = 1; off < NN; off <<= 1) {
        for (int i = tid; i < NN; i += 256) {
            int v = sA[i];
            if (i >= off) v += sA[i - off];
            sB[i] = v;
        }
        __syncthreads();
        int* t = sA; sA = sB; sB = t;
    }
    for (int i = tid; i < NN; i += 256) {
        int excl = (i == 0) ? 0 : sA[i - 1];
        fill[i] = excl;
        row_ofs[g * 513 + i] = excl;
    }
    if (tid == 0) row_ofs[g * 513 + NN] = sA[NN - 1];
    __syncthreads();
    for (int e = tid; e < NE; e += 256) {
        int d = dst[e];
        int pos = atomicAdd(&fill[d], 1);
        csr_src[(size_t)g * NE + pos] = src[e];
    }
}

// ---------------- K2/K4: Y = (X @ W) * rs_row  (fp32, 64-row tiles) ----------------
__device__ inline void fma4(float4& a, float s, const float4& w) {
    a.x += s * w.x; a.y += s * w.y; a.z += s * w.z; a.w += s * w.w;
}

__global__ __launch_bounds__(256) void k_gemm(const float* __restrict__ X,
                                              const float* __restrict__ W,
                                              const float* __restrict__ rs,
                                              float* __restrict__ Y) {
    __shared__ float xs[64][FH];   // 32 KB
    int tid = threadIdx.x;
    size_t r0 = (size_t)blockIdx.x * 64;

    // stage X tile (64x128 floats = 2048 float4), coalesced
    const float4* Xv = (const float4*)(X + r0 * FH);
    float4* xsv = (float4*)&xs[0][0];
#pragma unroll
    for (int i = 0; i < 8; i++) xsv[tid + i * 256] = Xv[tid + i * 256];
    __syncthreads();

    int tx = tid & 31;        // col group: 4 consecutive cols
    int ty = tid >> 5;        // row group: 8 consecutive rows
    int c4 = tx * 4;
    int row0 = ty * 8;

    float4 acc[8];
#pragma unroll
    for (int i = 0; i < 8; i++) acc[i] = make_float4(0.f, 0.f, 0.f, 0.f);

    for (int k = 0; k < FH; k += 4) {
        float4 w0 = *(const float4*)(W + (size_t)(k + 0) * FH + c4);
        float4 w1 = *(const float4*)(W + (size_t)(k + 1) * FH + c4);
        float4 w2 = *(const float4*)(W + (size_t)(k + 2) * FH + c4);
        float4 w3 = *(const float4*)(W + (size_t)(k + 3) * FH + c4);
#pragma unroll
        for (int i = 0; i < 8; i++) {
            float4 xv = *(const float4*)&xs[row0 + i][k];
            fma4(acc[i], xv.x, w0);
            fma4(acc[i], xv.y, w1);
            fma4(acc[i], xv.z, w2);
            fma4(acc[i], xv.w, w3);
        }
    }

#pragma unroll
    for (int i = 0; i < 8; i++) {
        size_t r = r0 + row0 + i;
        float s = rs[r];
        float4 v = acc[i];
        v.x *= s; v.y *= s; v.z *= s; v.w *= s;
        *(float4*)(Y + r * FH + c4) = v;
    }
}

// ---------------- K3: h[d] = relu(rs_in[d] * sum_{e in row(d)} Y[src_e] + b) ----------------
// One 32-lane group per dst node; each lane owns 4 consecutive floats (float4).
// 8-edge unroll -> 8 independent 16B loads in flight per lane.
__global__ __launch_bounds__(256) void k_gather(const float* __restrict__ Y,
                                                const int* __restrict__ row_ofs,
                                                const int* __restrict__ csr_src,
                                                const float* __restrict__ rs_in,
                                                const float* __restrict__ bias,
                                                float* __restrict__ H) {
    int g  = blockIdx.x;
    int bq = blockIdx.y;   // 0..7  block's 64-node slice
    int tid = threadIdx.x;
    int lane = tid & 31;   // float4 column 0..31
    int grp  = tid >> 5;   // 0..7
    const float4* Yv = (const float4*)(Y + (size_t)g * NN * FH);
    float4* Hv = (float4*)(H + (size_t)g * NN * FH);
    const int* ro = row_ofs + g * 513;
    const int* cs = csr_src + (size_t)g * NE;
    float4 bv = ((const float4*)bias)[lane];

    int dbase = bq * 64 + grp * 8;
    for (int di = 0; di < 8; di++) {
        int d = dbase + di;
        int e0 = ro[d], e1 = ro[d + 1];
        float4 a0 = make_float4(0.f,0.f,0.f,0.f), a1 = a0, a2 = a0, a3 = a0;
        int e = e0;
        for (; e + 8 <= e1; e += 8) {
            int s0 = cs[e],   s1 = cs[e+1], s2 = cs[e+2], s3 = cs[e+3];
            int s4 = cs[e+4], s5 = cs[e+5], s6 = cs[e+6], s7 = cs[e+7];
            float4 y0 = Yv[s0 * 32 + lane];
            float4 y1 = Yv[s1 * 32 + lane];
            float4 y2 = Yv[s2 * 32 + lane];
            float4 y3 = Yv[s3 * 32 + lane];
            float4 y4 = Yv[s4 * 32 + lane];
            float4 y5 = Yv[s5 * 32 + lane];
            float4 y6 = Yv[s6 * 32 + lane];
            float4 y7 = Yv[s7 * 32 + lane];
            f4acc(a0, y0); f4acc(a1, y1); f4acc(a2, y2); f4acc(a3, y3);
            f4acc(a0, y4); f4acc(a1, y5); f4acc(a2, y6); f4acc(a3, y7);
        }
        for (; e + 4 <= e1; e += 4) {
            int s0 = cs[e], s1 = cs[e+1], s2 = cs[e+2], s3 = cs[e+3];
            float4 y0 = Yv[s0 * 32 + lane];
            float4 y1 = Yv[s1 * 32 + lane];
            float4 y2 = Yv[s2 * 32 + lane];
            float4 y3 = Yv[s3 * 32 + lane];
            f4acc(a0, y0); f4acc(a1, y1); f4acc(a2, y2); f4acc(a3, y3);
        }
        for (; e < e1; e++) f4acc(a0, Yv[cs[e] * 32 + lane]);
        float4 s;
        s.x = (a0.x + a1.x) + (a2.x + a3.x);
        s.y = (a0.y + a1.y) + (a2.y + a3.y);
        s.z = (a0.z + a1.z) + (a2.z + a3.z);
        s.w = (a0.w + a1.w) + (a2.w + a3.w);
        float r = rs_in[g * NN + d];
        float4 h;
        h.x = fmaxf(r * s.x + bv.x, 0.f);
        h.y = fmaxf(r * s.y + bv.y, 0.f);
        h.z = fmaxf(r * s.z + bv.z, 0.f);
        h.w = fmaxf(r * s.w + bv.w, 0.f);
        Hv[d * 32 + lane] = h;
    }
}

// ---------------- K5: gather2 + relu + partial node-sum per block ----------------
__global__ __launch_bounds__(256) void k_gather_mean(const float* __restrict__ Y,
                                                     const int* __restrict__ row_ofs,
                                                     const int* __restrict__ csr_src,
                                                     const float* __restrict__ rs_in,
                                                     const float* __restrict__ bias,
                                                     float* __restrict__ partial) {
    int g  = blockIdx.x;
    int bq = blockIdx.y;   // 0..7
    int tid = threadIdx.x;
    int lane = tid & 31;
    int grp  = tid >> 5;
    const float4* Yv = (const float4*)(Y + (size_t)g * NN * FH);
    const int* ro = row_ofs + g * 513;
    const int* cs = csr_src + (size_t)g * NE;
    float4 bv = ((const float4*)bias)[lane];

    float4 sum = make_float4(0.f,0.f,0.f,0.f);
    int dbase = bq * 64 + grp * 8;
    for (int di = 0; di < 8; di++) {
        int d = dbase + di;
        int e0 = ro[d], e1 = ro[d + 1];
        float4 a0 = make_float4(0.f,0.f,0.f,0.f), a1 = a0, a2 = a0, a3 = a0;
        int e = e0;
        for (; e + 8 <= e1; e += 8) {
            int s0 = cs[e],   s1 = cs[e+1], s2 = cs[e+2], s3 = cs[e+3];
            int s4 = cs[e+4], s5 = cs[e+5], s6 = cs[e+6], s7 = cs[e+7];
            float4 y0 = Yv[s0 * 32 + lane];
            float4 y1 = Yv[s1 * 32 + lane];
            float4 y2 = Yv[s2 * 32 + lane];
            float4 y3 = Yv[s3 * 32 + lane];
            float4 y4 = Yv[s4 * 32 + lane];
            float4 y5 = Yv[s5 * 32 + lane];
            float4 y6 = Yv[s6 * 32 + lane];
            float4 y7 = Yv[s7 * 32 + lane];
            f4acc(a0, y0); f4acc(a1, y1); f4acc(a2, y2); f4acc(a3, y3);
            f4acc(a0, y4); f4acc(a1, y5); f4acc(a2, y6); f4acc(a3, y7);
        }
        for (; e + 4 <= e1; e += 4) {
            int s0 = cs[e], s1 = cs[e+1], s2 = cs[e+2], s3 = cs[e+3];
            float4 y0 = Yv[s0 * 32 + lane];
            float4 y1 = Yv[s1 * 32 + lane];
            float4 y2 = Yv[s2 * 32 + lane];
            float4 y3 = Yv[s3 * 32 + lane];
            f4acc(a0, y0); f4acc(a1, y1); f4acc(a2, y2); f4acc(a3, y3);
        }
        for (; e < e1; e++) f4acc(a0, Yv[cs[e] * 32 + lane]);
        float4 s;
        s.x = (a0.x + a1.x) + (a2.x + a3.x);
        s.y = (a0.y + a1.y) + (a2.y + a3.y);
        s.z = (a0.z + a1.z) + (a2.z + a3.z);
        s.w = (a0.w + a1.w) + (a2.w + a3.w);
        float r = rs_in[g * NN + d];
        sum.x += fmaxf(r * s.x + bv.x, 0.f);
        sum.y += fmaxf(r * s.y + bv.y, 0.f);
        sum.z += fmaxf(r * s.z + bv.z, 0.f);
        sum.w += fmaxf(r * s.w + bv.w, 0.f);
    }

    __shared__ float4 red[8][32];
    red[grp][lane] = sum;
    __syncthreads();
    if (grp == 0) {
        float4 t = red[0][lane];
#pragma unroll
        for (int j = 1; j < 8; j++) f4acc(t, red[j][lane]);
        ((float4*)partial)[((size_t)g * 8 + bq) * 32 + lane] = t;
    }
}

// ---------------- K6: z = (sum partials)/512 @ Wt + bt; BN eval; relu ----------------
__global__ __launch_bounds__(128) void k_head(const float* __restrict__ partial,
                                              const float* __restrict__ Wt,
                                              const float* __restrict__ bt,
                                              const float* __restrict__ gamma,
                                              const float* __restrict__ beta,
                                              const float* __restrict__ rmean,
                                              const float* __restrict__ rvar,
                                              float* __restrict__ out) {
    int g = blockIdx.x;
    int j = threadIdx.x;
    __shared__ float e[FH];
    float acc8 = 0.f;
#pragma unroll
    for (int q = 0; q < 8; q++) acc8 += partial[((size_t)g * 8 + q) * FH + j];
    e[j] = acc8 * (1.0f / (float)NN);
    __syncthreads();
    float acc = bt[j];
    for (int k = 0; k < FH; k++) acc += e[k] * Wt[(size_t)k * FH + j];
    float z = gamma[j] * (acc - rmean[j]) * rsqrtf(rvar[j] + BN_EPS) + beta[j];
    out[g * FH + j] = fmaxf(z, 0.f);
}

extern "C" void kernel_launch(void* const* d_in, const int* in_sizes, int n_in,
                              void* d_out, int out_size, void* d_ws, size_t ws_size,
                              hipStream_t stream) {
    const float* feats = (const float*)d_in[0];
    const int*   edges = (const int*)d_in[1];
    const float* W0    = (const float*)d_in[2];
    const float* b0    = (const float*)d_in[3];
    const float* W1    = (const float*)d_in[4];
    const float* b1    = (const float*)d_in[5];
    const float* Wt    = (const float*)d_in[6];
    const float* bt    = (const float*)d_in[7];
    const float* gamma = (const float*)d_in[8];
    const float* beta  = (const float*)d_in[9];
    const float* rmean = (const float*)d_in[10];
    const float* rvar  = (const float*)d_in[11];
    float* out = (float*)d_out;

    // workspace layout (all sizes in elements)
    char* w = (char*)d_ws;
    float* rs_out  = (float*)w;                     w += sizeof(float) * NG * NN;        // 256 KB
    float* rs_in   = (float*)w;                     w += sizeof(float) * NG * NN;        // 256 KB
    int*   row_ofs = (int*)w;                       w += sizeof(int) * NG * 520;         // ~266 KB
    int*   csr_src = (int*)w;                       w += sizeof(int) * (size_t)NG * NE;  // 4 MB
    float* Y       = (float*)w;                     w += sizeof(float) * (size_t)NG * NN * FH; // 32 MB
    float* H1      = (float*)w;                     w += sizeof(float) * (size_t)NG * NN * FH; // 32 MB
    float* partial = (float*)w;                     w += sizeof(float) * NG * 8 * FH;    // 512 KB

    // K1: build norms + CSR
    k_build<<<NG, 256, 0, stream>>>(edges, rs_out, rs_in, row_ofs, csr_src);

    // K2: Y = (feats @ W0) * rs_out
    k_gemm<<<(NG * NN) / 64, 256, 0, stream>>>(feats, W0, rs_out, Y);

    // K3: h1 = relu(rs_in * gather(Y) + b0)
    k_gather<<<dim3(NG, 8), 256, 0, stream>>>(Y, row_ofs, csr_src, rs_in, b0, H1);

    // K4: Y = (h1 @ W1) * rs_out
    k_gemm<<<(NG * NN) / 64, 256, 0, stream>>>(H1, W1, rs_out, Y);

    // K5: partial[g][bq] = sum_d relu(rs_in * gather(Y) + b1) over block's 64 nodes
    k_gather_mean<<<dim3(NG, 8), 256, 0, stream>>>(Y, row_ofs, csr_src, rs_in, b1, partial);

    // K6: per-graph sum partials -> mean -> GEMV + BN + relu
    k_head<<<NG, 128, 0, stream>>>(partial, Wt, bt, gamma, beta, rmean, rvar, out);

    (void)in_sizes; (void)n_in; (void)out_size; (void)ws_size;
}

// Round 3
// 265.559 us; speedup vs baseline: 1.3147x; 1.0418x over previous
//
#include <hip/hip_runtime.h>
#include <hip/hip_bf16.h>

#define NN 512      // nodes per graph
#define NE 8192     // edges per graph
#define NG 128      // graphs (B*G)
#define FH 128      // feature/hidden dim
#define FQ 32       // feature quarter handled per gather block
#define BN_EPS 1e-5f

__device__ inline void f4acc(float4& a, const float4& b) {
    a.x += b.x; a.y += b.y; a.z += b.z; a.w += b.w;
}

// ---------------- K1: degrees + rsqrt norms + CSR (by dst) build ----------------
// CSR fill happens in LDS (random 4B scatter stays on-chip), then coalesced copy out.
__global__ __launch_bounds__(256) void k_build(const int* __restrict__ edges,
                                               float* __restrict__ rs_out,
                                               float* __restrict__ rs_in,
                                               int* __restrict__ row_ofs,
                                               int* __restrict__ csr_src) {
    int g = blockIdx.x;
    int tid = threadIdx.x;
    const int* src = edges + (size_t)g * 2 * NE;
    const int* dst = src + NE;

    __shared__ int degO[NN], degI[NN];
    __shared__ int scanA[NN], scanB[NN];
    __shared__ int fill[NN];
    __shared__ int csr_lds[NE];          // 32 KB

    for (int i = tid; i < NN; i += 256) { degO[i] = 0; degI[i] = 0; }
    __syncthreads();
    for (int e = tid; e < NE; e += 256) {
        atomicAdd(&degO[src[e]], 1);
        atomicAdd(&degI[dst[e]], 1);
    }
    __syncthreads();
    for (int i = tid; i < NN; i += 256) {
        int dO = degO[i], dI = degI[i];
        rs_out[g * NN + i] = rsqrtf((float)max(dO, 1));
        rs_in [g * NN + i] = rsqrtf((float)max(dI, 1));
        scanA[i] = dI;
    }
    __syncthreads();
    // Hillis-Steele inclusive scan over 512 in-degrees (double-buffered)
    int* sA = scanA; int* sB = scanB;
    for (int off = 1; off < NN; off <<= 1) {
        for (int i = tid; i < NN; i += 256) {
            int v = sA[i];
            if (i >= off) v += sA[i - off];
            sB[i] = v;
        }
        __syncthreads();
        int* t = sA; sA = sB; sB = t;
    }
    for (int i = tid; i < NN; i += 256) {
        int excl = (i == 0) ? 0 : sA[i - 1];
        fill[i] = excl;
        row_ofs[g * 513 + i] = excl;
    }
    if (tid == 0) row_ofs[g * 513 + NN] = sA[NN - 1];
    __syncthreads();
    for (int e = tid; e < NE; e += 256) {
        int d = dst[e];
        int pos = atomicAdd(&fill[d], 1);
        csr_lds[pos] = src[e];
    }
    __syncthreads();
    for (int i = tid; i < NE; i += 256)
        csr_src[(size_t)g * NE + i] = csr_lds[i];
}

// ---------------- K2/K4: Y = (X @ W) * rs_row  (fp32, 64-row tiles) ----------------
__device__ inline void fma4(float4& a, float s, const float4& w) {
    a.x += s * w.x; a.y += s * w.y; a.z += s * w.z; a.w += s * w.w;
}

__global__ __launch_bounds__(256) void k_gemm(const float* __restrict__ X,
                                              const float* __restrict__ W,
                                              const float* __restrict__ rs,
                                              float* __restrict__ Y) {
    __shared__ float xs[64][FH];   // 32 KB
    int tid = threadIdx.x;
    size_t r0 = (size_t)blockIdx.x * 64;

    const float4* Xv = (const float4*)(X + r0 * FH);
    float4* xsv = (float4*)&xs[0][0];
#pragma unroll
    for (int i = 0; i < 8; i++) xsv[tid + i * 256] = Xv[tid + i * 256];
    __syncthreads();

    int tx = tid & 31;        // col group: 4 consecutive cols
    int ty = tid >> 5;        // row group: 8 consecutive rows
    int c4 = tx * 4;
    int row0 = ty * 8;

    float4 acc[8];
#pragma unroll
    for (int i = 0; i < 8; i++) acc[i] = make_float4(0.f, 0.f, 0.f, 0.f);

    for (int k = 0; k < FH; k += 4) {
        float4 w0 = *(const float4*)(W + (size_t)(k + 0) * FH + c4);
        float4 w1 = *(const float4*)(W + (size_t)(k + 1) * FH + c4);
        float4 w2 = *(const float4*)(W + (size_t)(k + 2) * FH + c4);
        float4 w3 = *(const float4*)(W + (size_t)(k + 3) * FH + c4);
#pragma unroll
        for (int i = 0; i < 8; i++) {
            float4 xv = *(const float4*)&xs[row0 + i][k];
            fma4(acc[i], xv.x, w0);
            fma4(acc[i], xv.y, w1);
            fma4(acc[i], xv.z, w2);
            fma4(acc[i], xv.w, w3);
        }
    }

#pragma unroll
    for (int i = 0; i < 8; i++) {
        size_t r = r0 + row0 + i;
        float s = rs[r];
        float4 v = acc[i];
        v.x *= s; v.y *= s; v.z *= s; v.w *= s;
        *(float4*)(Y + r * FH + c4) = v;
    }
}

// ---------------- K3: LDS-staged gather ----------------
// One block per (graph, feature-quarter). Stage Y[g][:, q*32:(q+1)*32] (64 KB) into
// LDS, then every edge-row read is a conflict-free ds_read_b128.
// 32 groups of 8 lanes; group owns 16 dst nodes; lane owns 4 consecutive feats.
__global__ __launch_bounds__(256) void k_gather(const float* __restrict__ Y,
                                                const int* __restrict__ row_ofs,
                                                const int* __restrict__ csr_src,
                                                const float* __restrict__ rs_in,
                                                const float* __restrict__ bias,
                                                float* __restrict__ H) {
    int g  = blockIdx.x;
    int fq = blockIdx.y;   // 0..3
    int tid = threadIdx.x;
    int l8  = tid & 7;     // lane in group
    int grp = tid >> 3;    // 0..31

    __shared__ float ys[NN][FQ];   // 64 KB
    const float* Yg = Y + (size_t)g * NN * FH + fq * FQ;

    // stage: wave covers 8 rows x 128B contiguous segments
    for (int r = grp; r < NN; r += 32)
        *(float4*)&ys[r][l8 * 4] = *(const float4*)(Yg + (size_t)r * FH + l8 * 4);
    __syncthreads();

    const int* ro = row_ofs + g * 513;
    const int* cs = csr_src + (size_t)g * NE;
    float4 bv = *(const float4*)(bias + fq * FQ + l8 * 4);
    float* Hg = H + (size_t)g * NN * FH + fq * FQ;

    for (int di = 0; di < 16; di++) {
        int d = grp * 16 + di;
        int e0 = ro[d], e1 = ro[d + 1];
        float4 a0 = make_float4(0.f,0.f,0.f,0.f), a1 = a0, a2 = a0, a3 = a0;
        int e = e0;
        for (; e + 8 <= e1; e += 8) {
            int s0 = cs[e],   s1 = cs[e+1], s2 = cs[e+2], s3 = cs[e+3];
            int s4 = cs[e+4], s5 = cs[e+5], s6 = cs[e+6], s7 = cs[e+7];
            float4 y0 = *(float4*)&ys[s0][l8*4];
            float4 y1 = *(float4*)&ys[s1][l8*4];
            float4 y2 = *(float4*)&ys[s2][l8*4];
            float4 y3 = *(float4*)&ys[s3][l8*4];
            float4 y4 = *(float4*)&ys[s4][l8*4];
            float4 y5 = *(float4*)&ys[s5][l8*4];
            float4 y6 = *(float4*)&ys[s6][l8*4];
            float4 y7 = *(float4*)&ys[s7][l8*4];
            f4acc(a0, y0); f4acc(a1, y1); f4acc(a2, y2); f4acc(a3, y3);
            f4acc(a0, y4); f4acc(a1, y5); f4acc(a2, y6); f4acc(a3, y7);
        }
        for (; e + 4 <= e1; e += 4) {
            int s0 = cs[e], s1 = cs[e+1], s2 = cs[e+2], s3 = cs[e+3];
            f4acc(a0, *(float4*)&ys[s0][l8*4]);
            f4acc(a1, *(float4*)&ys[s1][l8*4]);
            f4acc(a2, *(float4*)&ys[s2][l8*4]);
            f4acc(a3, *(float4*)&ys[s3][l8*4]);
        }
        for (; e < e1; e++) f4acc(a0, *(float4*)&ys[cs[e]][l8*4]);
        float4 s;
        s.x = (a0.x + a1.x) + (a2.x + a3.x);
        s.y = (a0.y + a1.y) + (a2.y + a3.y);
        s.z = (a0.z + a1.z) + (a2.z + a3.z);
        s.w = (a0.w + a1.w) + (a2.w + a3.w);
        float r = rs_in[g * NN + d];
        float4 h;
        h.x = fmaxf(r * s.x + bv.x, 0.f);
        h.y = fmaxf(r * s.y + bv.y, 0.f);
        h.z = fmaxf(r * s.z + bv.z, 0.f);
        h.w = fmaxf(r * s.w + bv.w, 0.f);
        *(float4*)(Hg + (size_t)d * FH + l8 * 4) = h;
    }
}

// ---------------- K5: LDS-staged gather2 + fused node-sum -> emb ----------------
// Same structure as K3; each block owns disjoint (graph, 32-feature) slice of emb,
// so the node-sum reduction completes in-block (no atomics, no partial pass).
__global__ __launch_bounds__(256) void k_gather_mean(const float* __restrict__ Y,
                                                     const int* __restrict__ row_ofs,
                                                     const int* __restrict__ csr_src,
                                                     const float* __restrict__ rs_in,
                                                     const float* __restrict__ bias,
                                                     float* __restrict__ emb) {
    int g  = blockIdx.x;
    int fq = blockIdx.y;
    int tid = threadIdx.x;
    int l8  = tid & 7;
    int grp = tid >> 3;

    __shared__ float ys[NN][FQ];        // 64 KB
    __shared__ float4 red[32][8];       // 4 KB
    const float* Yg = Y + (size_t)g * NN * FH + fq * FQ;

    for (int r = grp; r < NN; r += 32)
        *(float4*)&ys[r][l8 * 4] = *(const float4*)(Yg + (size_t)r * FH + l8 * 4);
    __syncthreads();

    const int* ro = row_ofs + g * 513;
    const int* cs = csr_src + (size_t)g * NE;
    float4 bv = *(const float4*)(bias + fq * FQ + l8 * 4);

    float4 sum = make_float4(0.f,0.f,0.f,0.f);
    for (int di = 0; di < 16; di++) {
        int d = grp * 16 + di;
        int e0 = ro[d], e1 = ro[d + 1];
        float4 a0 = make_float4(0.f,0.f,0.f,0.f), a1 = a0, a2 = a0, a3 = a0;
        int e = e0;
        for (; e + 8 <= e1; e += 8) {
            int s0 = cs[e],   s1 = cs[e+1], s2 = cs[e+2], s3 = cs[e+3];
            int s4 = cs[e+4], s5 = cs[e+5], s6 = cs[e+6], s7 = cs[e+7];
            float4 y0 = *(float4*)&ys[s0][l8*4];
            float4 y1 = *(float4*)&ys[s1][l8*4];
            float4 y2 = *(float4*)&ys[s2][l8*4];
            float4 y3 = *(float4*)&ys[s3][l8*4];
            float4 y4 = *(float4*)&ys[s4][l8*4];
            float4 y5 = *(float4*)&ys[s5][l8*4];
            float4 y6 = *(float4*)&ys[s6][l8*4];
            float4 y7 = *(float4*)&ys[s7][l8*4];
            f4acc(a0, y0); f4acc(a1, y1); f4acc(a2, y2); f4acc(a3, y3);
            f4acc(a0, y4); f4acc(a1, y5); f4acc(a2, y6); f4acc(a3, y7);
        }
        for (; e + 4 <= e1; e += 4) {
            int s0 = cs[e], s1 = cs[e+1], s2 = cs[e+2], s3 = cs[e+3];
            f4acc(a0, *(float4*)&ys[s0][l8*4]);
            f4acc(a1, *(float4*)&ys[s1][l8*4]);
            f4acc(a2, *(float4*)&ys[s2][l8*4]);
            f4acc(a3, *(float4*)&ys[s3][l8*4]);
        }
        for (; e < e1; e++) f4acc(a0, *(float4*)&ys[cs[e]][l8*4]);
        float4 s;
        s.x = (a0.x + a1.x) + (a2.x + a3.x);
        s.y = (a0.y + a1.y) + (a2.y + a3.y);
        s.z = (a0.z + a1.z) + (a2.z + a3.z);
        s.w = (a0.w + a1.w) + (a2.w + a3.w);
        float r = rs_in[g * NN + d];
        sum.x += fmaxf(r * s.x + bv.x, 0.f);
        sum.y += fmaxf(r * s.y + bv.y, 0.f);
        sum.z += fmaxf(r * s.z + bv.z, 0.f);
        sum.w += fmaxf(r * s.w + bv.w, 0.f);
    }

    red[grp][l8] = sum;
    __syncthreads();
    if (tid < 8) {
        float4 t = red[0][tid];
#pragma unroll
        for (int j = 1; j < 32; j++) f4acc(t, red[j][tid]);
        *(float4*)(emb + (size_t)g * FH + fq * FQ + tid * 4) = t;
    }
}

// ---------------- K6: z = emb/512 @ Wt + bt; BN eval; relu ----------------
__global__ __launch_bounds__(128) void k_head(const float* __restrict__ emb,
                                              const float* __restrict__ Wt,
                                              const float* __restrict__ bt,
                                              const float* __restrict__ gamma,
                                              const float* __restrict__ beta,
                                              const float* __restrict__ rmean,
                                              const float* __restrict__ rvar,
                                              float* __restrict__ out) {
    int g = blockIdx.x;
    int j = threadIdx.x;
    __shared__ float e[FH];
    e[j] = emb[(size_t)g * FH + j] * (1.0f / (float)NN);
    __syncthreads();
    float acc = bt[j];
    for (int k = 0; k < FH; k++) acc += e[k] * Wt[(size_t)k * FH + j];
    float z = gamma[j] * (acc - rmean[j]) * rsqrtf(rvar[j] + BN_EPS) + beta[j];
    out[g * FH + j] = fmaxf(z, 0.f);
}

extern "C" void kernel_launch(void* const* d_in, const int* in_sizes, int n_in,
                              void* d_out, int out_size, void* d_ws, size_t ws_size,
                              hipStream_t stream) {
    const float* feats = (const float*)d_in[0];
    const int*   edges = (const int*)d_in[1];
    const float* W0    = (const float*)d_in[2];
    const float* b0    = (const float*)d_in[3];
    const float* W1    = (const float*)d_in[4];
    const float* b1    = (const float*)d_in[5];
    const float* Wt    = (const float*)d_in[6];
    const float* bt    = (const float*)d_in[7];
    const float* gamma = (const float*)d_in[8];
    const float* beta  = (const float*)d_in[9];
    const float* rmean = (const float*)d_in[10];
    const float* rvar  = (const float*)d_in[11];
    float* out = (float*)d_out;

    // workspace layout
    char* w = (char*)d_ws;
    float* rs_out  = (float*)w;                     w += sizeof(float) * NG * NN;
    float* rs_in   = (float*)w;                     w += sizeof(float) * NG * NN;
    int*   row_ofs = (int*)w;                       w += sizeof(int) * NG * 520;
    int*   csr_src = (int*)w;                       w += sizeof(int) * (size_t)NG * NE;
    float* Y       = (float*)w;                     w += sizeof(float) * (size_t)NG * NN * FH;
    float* H1      = (float*)w;                     w += sizeof(float) * (size_t)NG * NN * FH;
    float* emb     = (float*)w;                     w += sizeof(float) * NG * FH;

    // K1: build norms + CSR
    k_build<<<NG, 256, 0, stream>>>(edges, rs_out, rs_in, row_ofs, csr_src);

    // K2: Y = (feats @ W0) * rs_out
    k_gemm<<<(NG * NN) / 64, 256, 0, stream>>>(feats, W0, rs_out, Y);

    // K3: h1 = relu(rs_in * gather(Y) + b0)
    k_gather<<<dim3(NG, 4), 256, 0, stream>>>(Y, row_ofs, csr_src, rs_in, b0, H1);

    // K4: Y = (h1 @ W1) * rs_out
    k_gemm<<<(NG * NN) / 64, 256, 0, stream>>>(H1, W1, rs_out, Y);

    // K5: emb[g][fq-slice] = sum_d relu(rs_in * gather(Y) + b1)
    k_gather_mean<<<dim3(NG, 4), 256, 0, stream>>>(Y, row_ofs, csr_src, rs_in, b1, emb);

    // K6: per-graph mean -> GEMV + BN + relu
    k_head<<<NG, 128, 0, stream>>>(emb, Wt, bt, gamma, beta, rmean, rvar, out);

    (void)in_sizes; (void)n_in; (void)out_size; (void)ws_size;
}

// Round 4
// 253.287 us; speedup vs baseline: 1.3784x; 1.0484x over previous
//
#include <hip/hip_runtime.h>
#include <hip/hip_bf16.h>

#define NN 512      // nodes per graph
#define NE 8192     // edges per graph
#define NG 128      // graphs (B*G)
#define FH 128      // feature/hidden dim
#define FQ 16       // feature slice per gather block (8 slices)
#define NSEG 64     // edge-balanced node segments per graph
#define BN_EPS 1e-5f

__device__ inline void f4acc(float4& a, const float4& b) {
    a.x += b.x; a.y += b.y; a.z += b.z; a.w += b.w;
}

// ---------------- K1: degrees + norms + CSR build + edge-balanced segments ----------------
__global__ __launch_bounds__(256) void k_build(const int* __restrict__ edges,
                                               float* __restrict__ rs_out,
                                               float* __restrict__ rs_in,
                                               int* __restrict__ row_ofs,
                                               int* __restrict__ csr_src,
                                               int* __restrict__ seg) {
    int g = blockIdx.x;
    int tid = threadIdx.x;
    const int* src = edges + (size_t)g * 2 * NE;
    const int* dst = src + NE;

    __shared__ int degO[NN], degI[NN];
    __shared__ int scanA[NN], scanB[NN];
    __shared__ int fill[NN];
    __shared__ int csr_lds[NE];          // 32 KB

    for (int i = tid; i < NN; i += 256) { degO[i] = 0; degI[i] = 0; }
    __syncthreads();
    for (int e = tid; e < NE; e += 256) {
        atomicAdd(&degO[src[e]], 1);
        atomicAdd(&degI[dst[e]], 1);
    }
    __syncthreads();
    for (int i = tid; i < NN; i += 256) {
        int dO = degO[i], dI = degI[i];
        rs_out[g * NN + i] = rsqrtf((float)max(dO, 1));
        rs_in [g * NN + i] = rsqrtf((float)max(dI, 1));
        scanA[i] = dI;
    }
    __syncthreads();
    // Hillis-Steele inclusive scan over 512 in-degrees
    int* sA = scanA; int* sB = scanB;
    for (int off = 1; off < NN; off <<= 1) {
        for (int i = tid; i < NN; i += 256) {
            int v = sA[i];
            if (i >= off) v += sA[i - off];
            sB[i] = v;
        }
        __syncthreads();
        int* t = sA; sA = sB; sB = t;
    }
    for (int i = tid; i < NN; i += 256) {
        int excl = (i == 0) ? 0 : sA[i - 1];
        fill[i] = excl;
        row_ofs[g * 513 + i] = excl;
    }
    if (tid == 0) row_ofs[g * 513 + NN] = sA[NN - 1];
    // edge-balanced segments: seg[j] = min i with excl_cum(i) >= j*(NE/NSEG)
    if (tid < NSEG) {
        int target = tid * (NE / NSEG);
        int lo = 0, hi = NN;
        while (lo < hi) {
            int mid = (lo + hi) >> 1;
            int ex = (mid == 0) ? 0 : sA[mid - 1];
            if (ex >= target) hi = mid; else lo = mid + 1;
        }
        seg[g * (NSEG + 1) + tid] = lo;
    }
    if (tid == 0) seg[g * (NSEG + 1) + NSEG] = NN;
    __syncthreads();
    for (int e = tid; e < NE; e += 256) {
        int d = dst[e];
        int pos = atomicAdd(&fill[d], 1);
        csr_lds[pos] = src[e];
    }
    __syncthreads();
    for (int i = tid; i < NE; i += 256)
        csr_src[(size_t)g * NE + i] = csr_lds[i];
}

// ---------------- K2/K4: Y = (X @ W) * rs_row  (fp32, 64-row tiles) ----------------
__device__ inline void fma4(float4& a, float s, const float4& w) {
    a.x += s * w.x; a.y += s * w.y; a.z += s * w.z; a.w += s * w.w;
}

__global__ __launch_bounds__(256) void k_gemm(const float* __restrict__ X,
                                              const float* __restrict__ W,
                                              const float* __restrict__ rs,
                                              float* __restrict__ Y) {
    __shared__ float xs[64][FH];   // 32 KB
    int tid = threadIdx.x;
    size_t r0 = (size_t)blockIdx.x * 64;

    const float4* Xv = (const float4*)(X + r0 * FH);
    float4* xsv = (float4*)&xs[0][0];
#pragma unroll
    for (int i = 0; i < 8; i++) xsv[tid + i * 256] = Xv[tid + i * 256];
    __syncthreads();

    int tx = tid & 31;
    int ty = tid >> 5;
    int c4 = tx * 4;
    int row0 = ty * 8;

    float4 acc[8];
#pragma unroll
    for (int i = 0; i < 8; i++) acc[i] = make_float4(0.f, 0.f, 0.f, 0.f);

    for (int k = 0; k < FH; k += 4) {
        float4 w0 = *(const float4*)(W + (size_t)(k + 0) * FH + c4);
        float4 w1 = *(const float4*)(W + (size_t)(k + 1) * FH + c4);
        float4 w2 = *(const float4*)(W + (size_t)(k + 2) * FH + c4);
        float4 w3 = *(const float4*)(W + (size_t)(k + 3) * FH + c4);
#pragma unroll
        for (int i = 0; i < 8; i++) {
            float4 xv = *(const float4*)&xs[row0 + i][k];
            fma4(acc[i], xv.x, w0);
            fma4(acc[i], xv.y, w1);
            fma4(acc[i], xv.z, w2);
            fma4(acc[i], xv.w, w3);
        }
    }

#pragma unroll
    for (int i = 0; i < 8; i++) {
        size_t r = r0 + row0 + i;
        float s = rs[r];
        float4 v = acc[i];
        v.x *= s; v.y *= s; v.z *= s; v.w *= s;
        *(float4*)(Y + r * FH + c4) = v;
    }
}

// ---------------- K3: LDS-staged gather, edge-balanced segments ----------------
// Block = (graph, 16-feature slice). 64 groups of 4 lanes; group walks one
// edge-balanced node segment (~128 edges); lane owns 4 consecutive feats.
__global__ __launch_bounds__(256) void k_gather(const float* __restrict__ Y,
                                                const int* __restrict__ row_ofs,
                                                const int* __restrict__ csr_src,
                                                const int* __restrict__ seg,
                                                const float* __restrict__ rs_in,
                                                const float* __restrict__ bias,
                                                float* __restrict__ H) {
    int g  = blockIdx.x;
    int fq = blockIdx.y;   // 0..7
    int tid = threadIdx.x;
    int l4  = tid & 3;
    int grp = tid >> 2;    // 0..63

    __shared__ float ys[NN][FQ];   // 32 KB
    const float* Yg = Y + (size_t)g * NN * FH + fq * FQ;

#pragma unroll
    for (int i = 0; i < 8; i++) {
        int u = tid + i * 256;     // 2048 float4 units
        int r = u >> 2, c = u & 3;
        *(float4*)&ys[r][c * 4] = *(const float4*)(Yg + (size_t)r * FH + c * 4);
    }
    __syncthreads();

    const int* ro = row_ofs + g * 513;
    const int* cs = csr_src + (size_t)g * NE;
    const int* sg = seg + g * (NSEG + 1);
    float4 bv = *(const float4*)(bias + fq * FQ + l4 * 4);
    float* Hg = H + (size_t)g * NN * FH + fq * FQ;

    int d0 = sg[grp], d1 = sg[grp + 1];
    for (int d = d0; d < d1; d++) {
        int e0 = ro[d], e1 = ro[d + 1];
        float4 a0 = make_float4(0.f,0.f,0.f,0.f), a1 = a0, a2 = a0, a3 = a0;
        int e = e0;
        for (; e < e1 && (e & 3); e++) f4acc(a0, *(float4*)&ys[cs[e]][l4 * 4]);
        for (; e + 8 <= e1; e += 8) {
            int4 i0 = *(const int4*)(cs + e);
            int4 i1 = *(const int4*)(cs + e + 4);
            float4 y0 = *(float4*)&ys[i0.x][l4*4];
            float4 y1 = *(float4*)&ys[i0.y][l4*4];
            float4 y2 = *(float4*)&ys[i0.z][l4*4];
            float4 y3 = *(float4*)&ys[i0.w][l4*4];
            float4 y4 = *(float4*)&ys[i1.x][l4*4];
            float4 y5 = *(float4*)&ys[i1.y][l4*4];
            float4 y6 = *(float4*)&ys[i1.z][l4*4];
            float4 y7 = *(float4*)&ys[i1.w][l4*4];
            f4acc(a0, y0); f4acc(a1, y1); f4acc(a2, y2); f4acc(a3, y3);
            f4acc(a0, y4); f4acc(a1, y5); f4acc(a2, y6); f4acc(a3, y7);
        }
        if (e + 4 <= e1) {
            int4 i0 = *(const int4*)(cs + e);
            f4acc(a0, *(float4*)&ys[i0.x][l4*4]);
            f4acc(a1, *(float4*)&ys[i0.y][l4*4]);
            f4acc(a2, *(float4*)&ys[i0.z][l4*4]);
            f4acc(a3, *(float4*)&ys[i0.w][l4*4]);
            e += 4;
        }
        for (; e < e1; e++) f4acc(a0, *(float4*)&ys[cs[e]][l4 * 4]);
        float4 s;
        s.x = (a0.x + a1.x) + (a2.x + a3.x);
        s.y = (a0.y + a1.y) + (a2.y + a3.y);
        s.z = (a0.z + a1.z) + (a2.z + a3.z);
        s.w = (a0.w + a1.w) + (a2.w + a3.w);
        float r = rs_in[g * NN + d];
        float4 h;
        h.x = fmaxf(r * s.x + bv.x, 0.f);
        h.y = fmaxf(r * s.y + bv.y, 0.f);
        h.z = fmaxf(r * s.z + bv.z, 0.f);
        h.w = fmaxf(r * s.w + bv.w, 0.f);
        *(float4*)(Hg + (size_t)d * FH + l4 * 4) = h;
    }
}

// ---------------- K5: LDS-staged gather2 + fused node-sum -> emb slice ----------------
__global__ __launch_bounds__(256) void k_gather_mean(const float* __restrict__ Y,
                                                     const int* __restrict__ row_ofs,
                                                     const int* __restrict__ csr_src,
                                                     const int* __restrict__ seg,
                                                     const float* __restrict__ rs_in,
                                                     const float* __restrict__ bias,
                                                     float* __restrict__ emb) {
    int g  = blockIdx.x;
    int fq = blockIdx.y;
    int tid = threadIdx.x;
    int l4  = tid & 3;
    int grp = tid >> 2;

    __shared__ float ys[NN][FQ];     // 32 KB
    __shared__ float4 red[NSEG][4];  // 4 KB
    const float* Yg = Y + (size_t)g * NN * FH + fq * FQ;

#pragma unroll
    for (int i = 0; i < 8; i++) {
        int u = tid + i * 256;
        int r = u >> 2, c = u & 3;
        *(float4*)&ys[r][c * 4] = *(const float4*)(Yg + (size_t)r * FH + c * 4);
    }
    __syncthreads();

    const int* ro = row_ofs + g * 513;
    const int* cs = csr_src + (size_t)g * NE;
    const int* sg = seg + g * (NSEG + 1);
    float4 bv = *(const float4*)(bias + fq * FQ + l4 * 4);

    float4 sum = make_float4(0.f,0.f,0.f,0.f);
    int d0 = sg[grp], d1 = sg[grp + 1];
    for (int d = d0; d < d1; d++) {
        int e0 = ro[d], e1 = ro[d + 1];
        float4 a0 = make_float4(0.f,0.f,0.f,0.f), a1 = a0, a2 = a0, a3 = a0;
        int e = e0;
        for (; e < e1 && (e & 3); e++) f4acc(a0, *(float4*)&ys[cs[e]][l4 * 4]);
        for (; e + 8 <= e1; e += 8) {
            int4 i0 = *(const int4*)(cs + e);
            int4 i1 = *(const int4*)(cs + e + 4);
            float4 y0 = *(float4*)&ys[i0.x][l4*4];
            float4 y1 = *(float4*)&ys[i0.y][l4*4];
            float4 y2 = *(float4*)&ys[i0.z][l4*4];
            float4 y3 = *(float4*)&ys[i0.w][l4*4];
            float4 y4 = *(float4*)&ys[i1.x][l4*4];
            float4 y5 = *(float4*)&ys[i1.y][l4*4];
            float4 y6 = *(float4*)&ys[i1.z][l4*4];
            float4 y7 = *(float4*)&ys[i1.w][l4*4];
            f4acc(a0, y0); f4acc(a1, y1); f4acc(a2, y2); f4acc(a3, y3);
            f4acc(a0, y4); f4acc(a1, y5); f4acc(a2, y6); f4acc(a3, y7);
        }
        if (e + 4 <= e1) {
            int4 i0 = *(const int4*)(cs + e);
            f4acc(a0, *(float4*)&ys[i0.x][l4*4]);
            f4acc(a1, *(float4*)&ys[i0.y][l4*4]);
            f4acc(a2, *(float4*)&ys[i0.z][l4*4]);
            f4acc(a3, *(float4*)&ys[i0.w][l4*4]);
            e += 4;
        }
        for (; e < e1; e++) f4acc(a0, *(float4*)&ys[cs[e]][l4 * 4]);
        float4 s;
        s.x = (a0.x + a1.x) + (a2.x + a3.x);
        s.y = (a0.y + a1.y) + (a2.y + a3.y);
        s.z = (a0.z + a1.z) + (a2.z + a3.z);
        s.w = (a0.w + a1.w) + (a2.w + a3.w);
        float r = rs_in[g * NN + d];
        sum.x += fmaxf(r * s.x + bv.x, 0.f);
        sum.y += fmaxf(r * s.y + bv.y, 0.f);
        sum.z += fmaxf(r * s.z + bv.z, 0.f);
        sum.w += fmaxf(r * s.w + bv.w, 0.f);
    }

    red[grp][l4] = sum;
    __syncthreads();
    if (tid < 4) {
        float4 t = red[0][tid];
#pragma unroll
        for (int j = 1; j < NSEG; j++) f4acc(t, red[j][tid]);
        *(float4*)(emb + (size_t)g * FH + fq * FQ + tid * 4) = t;
    }
}

// ---------------- K6: z = emb/512 @ Wt + bt; BN eval; relu ----------------
__global__ __launch_bounds__(128) void k_head(const float* __restrict__ emb,
                                              const float* __restrict__ Wt,
                                              const float* __restrict__ bt,
                                              const float* __restrict__ gamma,
                                              const float* __restrict__ beta,
                                              const float* __restrict__ rmean,
                                              const float* __restrict__ rvar,
                                              float* __restrict__ out) {
    int g = blockIdx.x;
    int j = threadIdx.x;
    __shared__ float e[FH];
    e[j] = emb[(size_t)g * FH + j] * (1.0f / (float)NN);
    __syncthreads();
    float acc = bt[j];
    for (int k = 0; k < FH; k++) acc += e[k] * Wt[(size_t)k * FH + j];
    float z = gamma[j] * (acc - rmean[j]) * rsqrtf(rvar[j] + BN_EPS) + beta[j];
    out[g * FH + j] = fmaxf(z, 0.f);
}

extern "C" void kernel_launch(void* const* d_in, const int* in_sizes, int n_in,
                              void* d_out, int out_size, void* d_ws, size_t ws_size,
                              hipStream_t stream) {
    const float* feats = (const float*)d_in[0];
    const int*   edges = (const int*)d_in[1];
    const float* W0    = (const float*)d_in[2];
    const float* b0    = (const float*)d_in[3];
    const float* W1    = (const float*)d_in[4];
    const float* b1    = (const float*)d_in[5];
    const float* Wt    = (const float*)d_in[6];
    const float* bt    = (const float*)d_in[7];
    const float* gamma = (const float*)d_in[8];
    const float* beta  = (const float*)d_in[9];
    const float* rmean = (const float*)d_in[10];
    const float* rvar  = (const float*)d_in[11];
    float* out = (float*)d_out;

    // workspace layout
    char* w = (char*)d_ws;
    float* rs_out  = (float*)w;                     w += sizeof(float) * NG * NN;
    float* rs_in   = (float*)w;                     w += sizeof(float) * NG * NN;
    int*   row_ofs = (int*)w;                       w += sizeof(int) * NG * 520;
    int*   seg     = (int*)w;                       w += sizeof(int) * NG * (NSEG + 1);
    int*   csr_src = (int*)w;                       w += sizeof(int) * (size_t)NG * NE;
    float* Y       = (float*)w;                     w += sizeof(float) * (size_t)NG * NN * FH;
    float* H1      = (float*)w;                     w += sizeof(float) * (size_t)NG * NN * FH;
    float* emb     = (float*)w;                     w += sizeof(float) * NG * FH;

    // K1: build norms + CSR + segments
    k_build<<<NG, 256, 0, stream>>>(edges, rs_out, rs_in, row_ofs, csr_src, seg);

    // K2: Y = (feats @ W0) * rs_out
    k_gemm<<<(NG * NN) / 64, 256, 0, stream>>>(feats, W0, rs_out, Y);

    // K3: h1 = relu(rs_in * gather(Y) + b0)
    k_gather<<<dim3(NG, FH / FQ), 256, 0, stream>>>(Y, row_ofs, csr_src, seg, rs_in, b0, H1);

    // K4: Y = (h1 @ W1) * rs_out
    k_gemm<<<(NG * NN) / 64, 256, 0, stream>>>(H1, W1, rs_out, Y);

    // K5: emb[g][fq-slice] = sum_d relu(rs_in * gather(Y) + b1)
    k_gather_mean<<<dim3(NG, FH / FQ), 256, 0, stream>>>(Y, row_ofs, csr_src, seg, rs_in, b1, emb);

    // K6: per-graph mean -> GEMV + BN + relu
    k_head<<<NG, 128, 0, stream>>>(emb, Wt, bt, gamma, beta, rmean, rvar, out);

    (void)in_sizes; (void)n_in; (void)out_size; (void)ws_size;
}